// Round 5
// baseline (538.045 us; speedup 1.0000x reference)
//
#include <hip/hip_runtime.h>
#include <stdint.h>

#define BN 4
#define SN 4096
#define EN 256
#define PN 32
#define FN 1024
#define BS (BN*SN)   // 16384
#define PAUG 64      // 32 xs chans + (-sq/2, 1) aug + zero pad to 64

typedef uint16_t bf16_t;
typedef short v4s  __attribute__((ext_vector_type(4)));
typedef short v8s  __attribute__((ext_vector_type(8)));
typedef __bf16 bf16x8 __attribute__((ext_vector_type(8)));
typedef float v4f   __attribute__((ext_vector_type(4)));

#define MFMA16(a,b,c) __builtin_amdgcn_mfma_f32_16x16x32_bf16(a,b,c,0,0,0)

__device__ __forceinline__ float b2f(bf16_t x){
    uint32_t u = ((uint32_t)x) << 16; float f; __builtin_memcpy(&f, &u, 4); return f;
}
__device__ __forceinline__ bf16_t f2b(float f){
    uint32_t u; __builtin_memcpy(&u, &f, 4);
    u += 0x7FFFu + ((u >> 16) & 1u);           // RNE
    return (bf16_t)(u >> 16);
}
__device__ __forceinline__ bf16x8 ldb8(const bf16_t* p){
    v8s r = *(const v8s*)p; return __builtin_bit_cast(bf16x8, r);
}
__device__ __forceinline__ float ldsc(const float* p){ return *p; }
__device__ __forceinline__ float ldsc(const bf16_t* p){ return b2f(*p); }
__device__ __forceinline__ void stsc(float* p, float v){ *p = v; }
__device__ __forceinline__ void stsc(bf16_t* p, float v){ *p = f2b(v); }

typedef const __attribute__((address_space(1))) uint32_t* glds_gp;
typedef __attribute__((address_space(3))) uint32_t* glds_lp;
__device__ __forceinline__ void glds16(const bf16_t* g, bf16_t* l){
    __builtin_amdgcn_global_load_lds((glds_gp)g, (glds_lp)l, 16, 0, 0);
}

// ---------------------------------------------------------------------------
// fp32 -> bf16 converters
// ---------------------------------------------------------------------------
__global__ __launch_bounds__(256) void cvt_kernel(
    const float* __restrict__ in, bf16_t* __restrict__ out)
{
    int i = (blockIdx.x * 256 + threadIdx.x) * 4;
    float4 f = *(const float4*)(in + i);
    v4s o;
    o.x = (short)f2b(f.x); o.y = (short)f2b(f.y);
    o.z = (short)f2b(f.z); o.w = (short)f2b(f.w);
    *(v4s*)(out + i) = o;
}

__global__ __launch_bounds__(256) void cvtw_kernel(
    const float* __restrict__ a, bf16_t* __restrict__ da,
    const float* __restrict__ b, bf16_t* __restrict__ db,
    const float* __restrict__ c, bf16_t* __restrict__ dc,
    const float* __restrict__ d, bf16_t* __restrict__ dd)
{
    int i = (blockIdx.x * 256 + threadIdx.x) * 4;
    const float* src; bf16_t* dst; int off;
    if      (i <  65536){ src=a; dst=da; off=i; }
    else if (i < 131072){ src=b; dst=db; off=i- 65536; }
    else if (i < 393216){ src=c; dst=dc; off=i-131072; }
    else                { src=d; dst=dd; off=i-393216; }
    float4 f = *(const float4*)(src + off);
    v4s o;
    o.x = (short)f2b(f.x); o.y = (short)f2b(f.y);
    o.z = (short)f2b(f.z); o.w = (short)f2b(f.w);
    *(v4s*)(dst + off) = o;
}

// ---------------------------------------------------------------------------
// posxs: pe = Wpos @ pos_embed + bpos; xs = pe/ls (bf16).
// Key rows [xs, -sq/2, 1, 0...], query rows [xs, 1, -sq/2, 0...] padded to 64
// so a 48-channel QK MFMA contraction yields -0.5*d2 directly.
// ---------------------------------------------------------------------------
__global__ __launch_bounds__(256) void posxs_kernel(
    const float* __restrict__ pos, const float* __restrict__ Wp,
    const float* __restrict__ bp,  const float* __restrict__ lsp,
    bf16_t* __restrict__ xk, bf16_t* __restrict__ xq)
{
    __shared__ float Wsh[PN*PN];
    __shared__ float bsh[PN];
    int tid = threadIdx.x;
    for (int i = tid; i < PN*PN; i += 256) Wsh[i] = Wp[i];
    if (tid < PN) bsh[tid] = bp[tid];
    __syncthreads();

    int s = blockIdx.x * 256 + tid;
    int b = blockIdx.y;
    float inv_ls = 1.0f / lsp[0];

    float col[PN];
    #pragma unroll
    for (int p = 0; p < PN; p++) col[p] = pos[((size_t)b*PN + p)*SN + s];

    uint16_t xb[PN];
    float sq = 0.f;
    #pragma unroll 4
    for (int o = 0; o < PN; o++){
        float pe = bsh[o];
        #pragma unroll
        for (int p = 0; p < PN; p++) pe += col[p] * Wsh[o*PN + p];
        uint16_t h = f2b(pe * inv_ls);
        xb[o] = h;
        float xr = b2f(h);
        sq += xr * xr;
    }
    uint16_t m05 = f2b(-0.5f * sq);
    const uint16_t one = 0x3F80;

    size_t base = ((size_t)b*SN + s) * PAUG;
    v8s pk[8];
    #pragma unroll
    for (int c = 0; c < 4; c++)
        #pragma unroll
        for (int j = 0; j < 8; j++) ((short*)&pk[c])[j] = (short)xb[c*8 + j];
    #pragma unroll
    for (int c = 4; c < 8; c++)
        #pragma unroll
        for (int j = 0; j < 8; j++) ((short*)&pk[c])[j] = 0;

    ((short*)&pk[4])[0] = (short)m05; ((short*)&pk[4])[1] = (short)one;
    #pragma unroll
    for (int c = 0; c < 8; c++) *(v8s*)(xk + base + c*8) = pk[c];

    ((short*)&pk[4])[0] = (short)one; ((short*)&pk[4])[1] = (short)m05;
    #pragma unroll
    for (int c = 0; c < 8; c++) *(v8s*)(xq + base + c*8) = pk[c];
}

// ---------------------------------------------------------------------------
// gemm_a: out = A @ W^T (+bias, opt relu). Block 64m x 64n, 4 waves on m.
// ENTIRE W-tile [64n x K] (K<=256 -> <=32 KB) staged via global_load_lds in
// layout [K/32][64n][32k]; ONE barrier; then barrier-free MFMA loop.
// EPI 0: bias ; 1: relu ; 3: bias -> transposed store vt[b][e][s]
// ---------------------------------------------------------------------------
template<int EPI, typename OutT>
__global__ __launch_bounds__(256) void gemm_a(
    const bf16_t* __restrict__ A, const bf16_t* __restrict__ W,
    const float* __restrict__ bias, OutT* __restrict__ out,
    bf16_t* __restrict__ vt, int M, int N, int K)
{
    __shared__ __align__(16) bf16_t Wt[8*2048];   // 32 KB max
    int tid = threadIdx.x;
    int lane = tid & 63, wv = tid >> 6, col = lane & 15, quad = lane >> 4;
    int m0 = blockIdx.x * 64, n0 = blockIdx.y * 64;
    int nck = K >> 5;

    const bf16_t* wsrc = W + (size_t)(n0 + (tid>>2))*K + (tid&3)*8;
    for (int r = 0; r < nck; r++)
        glds16(wsrc + r*32, Wt + r*2048 + tid*8);

    const bf16_t* Arow = A + (size_t)(m0 + wv*16 + col)*K + quad*8;

    v4f acc[4];
    #pragma unroll
    for (int t = 0; t < 4; t++) acc[t] = (v4f){0.f,0.f,0.f,0.f};

    __syncthreads();   // drains glds (vmcnt(0) implied)

    for (int c = 0; c < nck; c++){
        bf16x8 a = ldb8(Arow + c*32);
        #pragma unroll
        for (int t = 0; t < 4; t++){
            bf16x8 bf = ldb8(Wt + c*2048 + (t*16 + col)*32 + quad*8);
            acc[t] = MFMA16(a, bf, acc[t]);
        }
    }

    float bfv[4];
    #pragma unroll
    for (int t = 0; t < 4; t++) bfv[t] = bias[n0 + t*16 + col];

    if constexpr (EPI == 3){
        __shared__ uint16_t Tsh[64*74];
        #pragma unroll
        for (int r = 0; r < 4; r++)
            #pragma unroll
            for (int t = 0; t < 4; t++)
                Tsh[(wv*16 + quad*4 + r)*74 + t*16 + col] = f2b(acc[t][r] + bfv[t]);
        __syncthreads();
        int e = tid >> 2, sc = tid & 3;
        int b = m0 >> 12;
        int sl = (m0 & (SN-1)) + sc*16;
        v8s p0, p1;
        #pragma unroll
        for (int i = 0; i < 8; i++) ((short*)&p0)[i] = (short)Tsh[(sc*16 + i)*74 + e];
        #pragma unroll
        for (int i = 0; i < 8; i++) ((short*)&p1)[i] = (short)Tsh[(sc*16 + 8 + i)*74 + e];
        bf16_t* dst = vt + ((size_t)b*EN + n0 + e)*SN + sl;
        *(v8s*)dst = p0;
        *(v8s*)(dst + 8) = p1;
    } else {
        #pragma unroll
        for (int r = 0; r < 4; r++){
            int row = m0 + wv*16 + quad*4 + r;
            #pragma unroll
            for (int t = 0; t < 4; t++){
                float y = acc[t][r] + bfv[t];
                if constexpr (EPI == 1) y = fmaxf(y, 0.f);
                stsc(out + (size_t)row*N + n0 + t*16 + col, y);
            }
        }
    }
}

// ---------------------------------------------------------------------------
// gemm_ln: out = LayerNorm(A@W^T + bias + res), N=256. Barrier-light:
// block = 16m x 256n, 4 waves split n (64 each); W-frags direct from L2;
// LN stats via shfl + tiny LDS cross-wave combine. Grid = M/16 = 1024.
// ---------------------------------------------------------------------------
template<typename OutT, typename ResT>
__global__ __launch_bounds__(256, 4) void gemm_ln(
    const bf16_t* __restrict__ A, const bf16_t* __restrict__ W,
    const float* __restrict__ bias, const ResT* __restrict__ res,
    const float* __restrict__ gamma, const float* __restrict__ beta,
    OutT* __restrict__ out, int K)
{
    __shared__ float s1sh[4][16], s2sh[4][16];
    int tid = threadIdx.x;
    int lane = tid & 63, wv = tid >> 6, col = lane & 15, quad = lane >> 4;
    int m0 = blockIdx.x * 16;

    const bf16_t* Arow = A + (size_t)(m0 + col)*K + quad*8;
    const bf16_t* Wb   = W + (size_t)(wv*64 + col)*K + quad*8;

    v4f acc[4];
    #pragma unroll
    for (int t = 0; t < 4; t++) acc[t] = (v4f){0.f,0.f,0.f,0.f};

    for (int ks = 0; ks < K; ks += 32){
        bf16x8 a = ldb8(Arow + ks);
        #pragma unroll
        for (int t = 0; t < 4; t++){
            bf16x8 bf = ldb8(Wb + (size_t)t*16*K + ks);
            acc[t] = MFMA16(a, bf, acc[t]);
        }
    }

    float s1[4], s2[4];
    #pragma unroll
    for (int r = 0; r < 4; r++){
        int row = m0 + quad*4 + r;
        float s1v = 0.f, s2v = 0.f;
        #pragma unroll
        for (int t = 0; t < 4; t++){
            int n = wv*64 + t*16 + col;
            float y = acc[t][r] + bias[n] + ldsc(res + (size_t)row*EN + n);
            acc[t][r] = y;
            s1v += y; s2v += y*y;
        }
        #pragma unroll
        for (int m = 1; m <= 8; m <<= 1){
            s1v += __shfl_xor(s1v, m);
            s2v += __shfl_xor(s2v, m);
        }
        s1[r] = s1v; s2[r] = s2v;
    }
    if (col == 0){
        #pragma unroll
        for (int r = 0; r < 4; r++){
            s1sh[wv][quad*4 + r] = s1[r];
            s2sh[wv][quad*4 + r] = s2[r];
        }
    }
    __syncthreads();
    #pragma unroll
    for (int r = 0; r < 4; r++){
        int rw = quad*4 + r;
        float S1 = s1sh[0][rw] + s1sh[1][rw] + s1sh[2][rw] + s1sh[3][rw];
        float S2 = s2sh[0][rw] + s2sh[1][rw] + s2sh[2][rw] + s2sh[3][rw];
        float mu  = S1 * (1.f/256.f);
        float var = S2 * (1.f/256.f) - mu*mu;
        float rs  = rsqrtf(var + 1e-5f);
        #pragma unroll
        for (int t = 0; t < 4; t++){
            int n = wv*64 + t*16 + col;
            stsc(out + (size_t)(m0 + rw)*EN + n, (acc[t][r]-mu)*rs*gamma[n] + beta[n]);
        }
    }
}

// ---------------------------------------------------------------------------
// Attention: 16 queries/block, 4 waves k-split (1024 k each), 16x16x32 MFMAs.
// QK over 48 aug channels -> st = -0.5*d2; w = exp(os*exp(st)-os).
// C->A layout transform via wave-private LDS tile (no shuffles, no barriers).
// PV B-frags direct from pre-transposed Vt[b][e][s]. Chunked LDS combine.
// ---------------------------------------------------------------------------
__global__ __launch_bounds__(256, 3) void attn_kernel(
    const bf16_t* __restrict__ xk, const bf16_t* __restrict__ xq,
    const bf16_t* __restrict__ vt, const float* __restrict__ osp,
    bf16_t* __restrict__ ctx)
{
    __shared__ __align__(16) bf16_t wtile[4][16*40];  // 5 KB  (stride 40: 16B-aligned rows)
    __shared__ __align__(16) float cbuf[3][2048];     // 24 KB (8-et chunks)
    __shared__ float densh[4][16];

    int tid  = threadIdx.x;
    int lane = tid & 63;
    int wv   = tid >> 6;
    int col  = lane & 15;
    int quad = lane >> 4;

    // batch b pinned to XCD pair {2b,2b+1} -> Vt slice stays L2-resident
    int bid = blockIdx.x;
    int b   = (bid >> 1) & 3;
    int idx = ((bid >> 3) << 1) | (bid & 1);
    int q0  = idx * 16;

    float os = osp[0];
    const float c1 = 1.4426950408889634f;
    float k2 = c1 * os;

    const bf16_t* xkb = xk + (size_t)b * SN * PAUG;
    const bf16_t* xqb = xq + (size_t)b * SN * PAUG;
    const bf16_t* vtb = vt + (size_t)b * EN * SN;

    bf16x8 qf0 = ldb8(xqb + (size_t)(q0 + col)*PAUG + quad*8);
    bf16x8 qf1 = ldb8(xqb + (size_t)(q0 + col)*PAUG + 32 + quad*8);

    v4f acc[16];
    #pragma unroll
    for (int t = 0; t < 16; t++) acc[t] = (v4f){0.f,0.f,0.f,0.f};
    float den = 0.f;
    const v4f zero = (v4f){0.f,0.f,0.f,0.f};
    bf16_t* wt = &wtile[wv][0];

    int k0beg = wv * 1024;
    for (int k0 = k0beg; k0 < k0beg + 1024; k0 += 32){
        // QK: st[g] = scores for keys k0+16g..+15 x 16 queries (C: col=q, row=k)
        v4f st[2];
        #pragma unroll
        for (int g = 0; g < 2; g++){
            const bf16_t* krow = xkb + (size_t)(k0 + g*16 + col)*PAUG;
            bf16x8 kf0 = ldb8(krow + quad*8);
            bf16x8 kf1 = ldb8(krow + 32 + quad*8);
            st[g] = MFMA16(kf0, qf0, zero);
            st[g] = MFMA16(kf1, qf1, st[g]);
        }
        // w = exp(os*exp(st) - os); pack pairs -> wave-private LDS in A-layout order
        #pragma unroll
        for (int g = 0; g < 2; g++)
            #pragma unroll
            for (int rp = 0; rp < 2; rp++){
                float w0 = exp2f(fmaf(k2, exp2f(c1*st[g][rp*2+0]), -k2));
                float w1 = exp2f(fmaf(k2, exp2f(c1*st[g][rp*2+1]), -k2));
                den += w0 + w1;
                uint32_t pk = (uint32_t)f2b(w0) | ((uint32_t)f2b(w1) << 16);
                *(uint32_t*)&wt[col*40 + g*16 + quad*4 + rp*2] = pk;
            }
        // A-frag: lane(col=q, quad) reads k = quad*8..+7 (same-wave LDS, no barrier)
        bf16x8 af = ldb8(&wt[col*40 + quad*8]);
        #pragma unroll
        for (int et = 0; et < 16; et++){
            bf16x8 bf = ldb8(vtb + (size_t)(et*16 + col)*SN + k0 + quad*8);
            acc[et] = MFMA16(af, bf, acc[et]);
        }
    }

    // den: sum over quads -> per-q totals on lanes 0..15
    den += __shfl_xor(den, 16);
    den += __shfl_xor(den, 32);
    if (lane < 16) densh[wv][col] = den;
    __syncthreads();

    // cross-wave k-combine in two 8-et chunks
    #pragma unroll
    for (int ch = 0; ch < 2; ch++){
        if (wv > 0){
            #pragma unroll
            for (int e8 = 0; e8 < 8; e8++)
                *(v4f*)&cbuf[wv-1][e8*256 + lane*4] = acc[ch*8 + e8];
        }
        __syncthreads();
        if (wv == 0){
            #pragma unroll
            for (int e8 = 0; e8 < 8; e8++)
                #pragma unroll
                for (int w = 0; w < 3; w++){
                    v4f p = *(const v4f*)&cbuf[w][e8*256 + lane*4];
                    #pragma unroll
                    for (int j = 0; j < 4; j++) acc[ch*8 + e8][j] += p[j];
                }
        }
        __syncthreads();
    }

    if (wv == 0){
        float inv[4];
        #pragma unroll
        for (int r = 0; r < 4; r++){
            int rw = quad*4 + r;
            float dt = densh[0][rw] + densh[1][rw] + densh[2][rw] + densh[3][rw];
            inv[r] = 1.f / dt;
        }
        size_t obase = ((size_t)b*SN + q0) * EN;
        #pragma unroll
        for (int et = 0; et < 16; et++)
            #pragma unroll
            for (int r = 0; r < 4; r++)
                ctx[obase + (size_t)(quad*4 + r)*EN + et*16 + col] = f2b(acc[et][r] * inv[r]);
    }
}

// ---------------------------------------------------------------------------
extern "C" void kernel_launch(void* const* d_in, const int* in_sizes, int n_in,
                              void* d_out, int out_size, void* d_ws, size_t ws_size,
                              hipStream_t stream)
{
    (void)in_sizes; (void)n_in; (void)out_size; (void)ws_size;
    const float* src  = (const float*)d_in[0];
    const float* pos  = (const float*)d_in[1];
    const float* Wpos = (const float*)d_in[2];
    const float* bpos = (const float*)d_in[3];
    const float* ls   = (const float*)d_in[4];
    const float* os   = (const float*)d_in[5];
    const float* Wv   = (const float*)d_in[6];
    const float* bv   = (const float*)d_in[7];
    const float* Wo   = (const float*)d_in[8];
    const float* bo   = (const float*)d_in[9];
    const float* W1   = (const float*)d_in[10];
    const float* b1   = (const float*)d_in[11];
    const float* W2   = (const float*)d_in[12];
    const float* b2   = (const float*)d_in[13];
    const float* g1   = (const float*)d_in[14];
    const float* be1  = (const float*)d_in[15];
    const float* g2   = (const float*)d_in[16];
    const float* be2  = (const float*)d_in[17];

    char* w = (char*)d_ws;
    bf16_t* xkb  = (bf16_t*)(w);                         // 2 MB [B,S,64]
    bf16_t* xqb  = (bf16_t*)(w + ( 2u<<20));             // 2 MB
    bf16_t* Wvb  = (bf16_t*)(w + ( 4u<<20));             // 128 KB
    bf16_t* Wob  = (bf16_t*)(w + ( 4u<<20) + (1u<<18));  // 128 KB
    bf16_t* W1b  = (bf16_t*)(w + ( 5u<<20));             // 512 KB
    bf16_t* W2b  = (bf16_t*)(w + ( 6u<<20));             // 512 KB
    bf16_t* srcb = (bf16_t*)(w + ( 8u<<20));             // 8 MB (dead after vproj)
    bf16_t* ctx  = (bf16_t*)(w + ( 8u<<20));             // aliases srcb
    bf16_t* vtg  = (bf16_t*)(w + (16u<<20));             // 8 MB [B,E,S]
    bf16_t* xws  = (bf16_t*)(w + (24u<<20));             // 8 MB
    bf16_t* hws  = (bf16_t*)(w + (32u<<20));             // 32 MB

    cvt_kernel<<<dim3((BS*EN)>>10), 256, 0, stream>>>(src, srcb);
    cvtw_kernel<<<dim3(640), 256, 0, stream>>>(Wv, Wvb, Wo, Wob, W1, W1b, W2, W2b);
    posxs_kernel<<<dim3(SN/256, BN), 256, 0, stream>>>(pos, Wpos, bpos, ls, xkb, xqb);

    // v = src @ Wv^T + bv  -> transposed store vt[b][e][s]
    gemm_a<3, bf16_t><<<dim3(BS/64, EN/64), 256, 0, stream>>>(
        srcb, Wvb, bv, (bf16_t*)nullptr, vtg, BS, EN, EN);
    // ctx = softmax(os*exp(-0.5*d2)) @ v
    attn_kernel<<<dim3(1024), 256, 0, stream>>>(xkb, xqb, vtg, os, ctx);
    // x = LN1(src + ctx @ Wo^T + bo)
    gemm_ln<bf16_t, float><<<dim3(BS/16), 256, 0, stream>>>(
        ctx, Wob, bo, src, g1, be1, xws, EN);
    // h = relu(x @ W1^T + b1)
    gemm_a<1, bf16_t><<<dim3(BS/64, FN/64), 256, 0, stream>>>(
        xws, W1b, b1, hws, (bf16_t*)nullptr, BS, FN, EN);
    // out = LN2(x + h @ W2^T + b2) -> fp32
    gemm_ln<float, bf16_t><<<dim3(BS/16), 256, 0, stream>>>(
        hws, W2b, b2, xws, g2, be2, (float*)d_out, FN);
}

// Round 6
// 304.347 us; speedup vs baseline: 1.7679x; 1.7679x over previous
//
#include <hip/hip_runtime.h>
#include <stdint.h>

#define BN 4
#define SN 4096
#define EN 256
#define PN 32
#define FN 1024
#define BS (BN*SN)   // 16384
#define PAUG 64      // 32 xs chans + (-sq/2, 1) aug + zero pad to 64

typedef uint16_t bf16_t;
typedef short v4s  __attribute__((ext_vector_type(4)));
typedef short v8s  __attribute__((ext_vector_type(8)));
typedef __bf16 bf16x8 __attribute__((ext_vector_type(8)));
typedef float v4f   __attribute__((ext_vector_type(4)));
typedef float v16f  __attribute__((ext_vector_type(16)));

#define MFMA16(a,b,c) __builtin_amdgcn_mfma_f32_16x16x32_bf16(a,b,c,0,0,0)
#define MFMA32(a,b,c) __builtin_amdgcn_mfma_f32_32x32x16_bf16(a,b,c,0,0,0)

__device__ __forceinline__ float b2f(bf16_t x){
    uint32_t u = ((uint32_t)x) << 16; float f; __builtin_memcpy(&f, &u, 4); return f;
}
__device__ __forceinline__ bf16_t f2b(float f){
    uint32_t u; __builtin_memcpy(&u, &f, 4);
    u += 0x7FFFu + ((u >> 16) & 1u);           // RNE
    return (bf16_t)(u >> 16);
}
__device__ __forceinline__ bf16x8 ldb8(const bf16_t* p){
    v8s r = *(const v8s*)p; return __builtin_bit_cast(bf16x8, r);
}
__device__ __forceinline__ float ldsc(const float* p){ return *p; }
__device__ __forceinline__ float ldsc(const bf16_t* p){ return b2f(*p); }
__device__ __forceinline__ void stsc(float* p, float v){ *p = v; }
__device__ __forceinline__ void stsc(bf16_t* p, float v){ *p = f2b(v); }

typedef const __attribute__((address_space(1))) uint32_t* glds_gp;
typedef __attribute__((address_space(3))) uint32_t* glds_lp;
__device__ __forceinline__ void glds16(const bf16_t* g, bf16_t* l){
    __builtin_amdgcn_global_load_lds((glds_gp)g, (glds_lp)l, 16, 0, 0);
}

// ---------------------------------------------------------------------------
// fp32 -> bf16 converters
// ---------------------------------------------------------------------------
__global__ __launch_bounds__(256) void cvt_kernel(
    const float* __restrict__ in, bf16_t* __restrict__ out)
{
    int i = (blockIdx.x * 256 + threadIdx.x) * 4;
    float4 f = *(const float4*)(in + i);
    v4s o;
    o.x = (short)f2b(f.x); o.y = (short)f2b(f.y);
    o.z = (short)f2b(f.z); o.w = (short)f2b(f.w);
    *(v4s*)(out + i) = o;
}

__global__ __launch_bounds__(256) void cvtw_kernel(
    const float* __restrict__ a, bf16_t* __restrict__ da,
    const float* __restrict__ b, bf16_t* __restrict__ db,
    const float* __restrict__ c, bf16_t* __restrict__ dc,
    const float* __restrict__ d, bf16_t* __restrict__ dd)
{
    int i = (blockIdx.x * 256 + threadIdx.x) * 4;
    const float* src; bf16_t* dst; int off;
    if      (i <  65536){ src=a; dst=da; off=i; }
    else if (i < 131072){ src=b; dst=db; off=i- 65536; }
    else if (i < 393216){ src=c; dst=dc; off=i-131072; }
    else                { src=d; dst=dd; off=i-393216; }
    float4 f = *(const float4*)(src + off);
    v4s o;
    o.x = (short)f2b(f.x); o.y = (short)f2b(f.y);
    o.z = (short)f2b(f.z); o.w = (short)f2b(f.w);
    *(v4s*)(dst + off) = o;
}

// ---------------------------------------------------------------------------
// posxs: pe = Wpos @ pos_embed + bpos; xs = pe/ls (bf16).
// Key rows [xs, -sq/2, 1, 0...], query rows [xs, 1, -sq/2, 0...] padded to 64
// so a QK MFMA contraction over 64 chans yields -0.5*d2 directly.
// ---------------------------------------------------------------------------
__global__ __launch_bounds__(256) void posxs_kernel(
    const float* __restrict__ pos, const float* __restrict__ Wp,
    const float* __restrict__ bp,  const float* __restrict__ lsp,
    bf16_t* __restrict__ xk, bf16_t* __restrict__ xq)
{
    __shared__ float Wsh[PN*PN];
    __shared__ float bsh[PN];
    int tid = threadIdx.x;
    for (int i = tid; i < PN*PN; i += 256) Wsh[i] = Wp[i];
    if (tid < PN) bsh[tid] = bp[tid];
    __syncthreads();

    int s = blockIdx.x * 256 + tid;
    int b = blockIdx.y;
    float inv_ls = 1.0f / lsp[0];

    float col[PN];
    #pragma unroll
    for (int p = 0; p < PN; p++) col[p] = pos[((size_t)b*PN + p)*SN + s];

    uint16_t xb[PN];
    float sq = 0.f;
    #pragma unroll 4
    for (int o = 0; o < PN; o++){
        float pe = bsh[o];
        #pragma unroll
        for (int p = 0; p < PN; p++) pe += col[p] * Wsh[o*PN + p];
        uint16_t h = f2b(pe * inv_ls);
        xb[o] = h;
        float xr = b2f(h);
        sq += xr * xr;
    }
    uint16_t m05 = f2b(-0.5f * sq);
    const uint16_t one = 0x3F80;

    size_t base = ((size_t)b*SN + s) * PAUG;
    v8s pk[8];
    #pragma unroll
    for (int c = 0; c < 4; c++)
        #pragma unroll
        for (int j = 0; j < 8; j++) ((short*)&pk[c])[j] = (short)xb[c*8 + j];
    #pragma unroll
    for (int c = 4; c < 8; c++)
        #pragma unroll
        for (int j = 0; j < 8; j++) ((short*)&pk[c])[j] = 0;

    ((short*)&pk[4])[0] = (short)m05; ((short*)&pk[4])[1] = (short)one;
    #pragma unroll
    for (int c = 0; c < 8; c++) *(v8s*)(xk + base + c*8) = pk[c];

    ((short*)&pk[4])[0] = (short)one; ((short*)&pk[4])[1] = (short)m05;
    #pragma unroll
    for (int c = 0; c < 8; c++) *(v8s*)(xq + base + c*8) = pk[c];
}

// ---------------------------------------------------------------------------
// gemm_a: out = A @ W^T (+bias, opt relu). Block 64m x 64n, 4 waves on m.
// Entire W-tile [64n x K] staged once via global_load_lds; one barrier.
// EPI 0: bias ; 1: relu ; 3: bias -> transposed store vt[b][e][s]
// ---------------------------------------------------------------------------
template<int EPI, typename OutT>
__global__ __launch_bounds__(256) void gemm_a(
    const bf16_t* __restrict__ A, const bf16_t* __restrict__ W,
    const float* __restrict__ bias, OutT* __restrict__ out,
    bf16_t* __restrict__ vt, int M, int N, int K)
{
    __shared__ __align__(16) bf16_t Wt[8*2048];   // 32 KB max
    int tid = threadIdx.x;
    int lane = tid & 63, wv = tid >> 6, col = lane & 15, quad = lane >> 4;
    int m0 = blockIdx.x * 64, n0 = blockIdx.y * 64;
    int nck = K >> 5;

    const bf16_t* wsrc = W + (size_t)(n0 + (tid>>2))*K + (tid&3)*8;
    for (int r = 0; r < nck; r++)
        glds16(wsrc + r*32, Wt + r*2048 + tid*8);

    const bf16_t* Arow = A + (size_t)(m0 + wv*16 + col)*K + quad*8;

    v4f acc[4];
    #pragma unroll
    for (int t = 0; t < 4; t++) acc[t] = (v4f){0.f,0.f,0.f,0.f};

    __syncthreads();

    for (int c = 0; c < nck; c++){
        bf16x8 a = ldb8(Arow + c*32);
        #pragma unroll
        for (int t = 0; t < 4; t++){
            bf16x8 bf = ldb8(Wt + c*2048 + (t*16 + col)*32 + quad*8);
            acc[t] = MFMA16(a, bf, acc[t]);
        }
    }

    float bfv[4];
    #pragma unroll
    for (int t = 0; t < 4; t++) bfv[t] = bias[n0 + t*16 + col];

    if constexpr (EPI == 3){
        __shared__ uint16_t Tsh[64*74];
        #pragma unroll
        for (int r = 0; r < 4; r++)
            #pragma unroll
            for (int t = 0; t < 4; t++)
                Tsh[(wv*16 + quad*4 + r)*74 + t*16 + col] = f2b(acc[t][r] + bfv[t]);
        __syncthreads();
        int e = tid >> 2, sc = tid & 3;
        int b = m0 >> 12;
        int sl = (m0 & (SN-1)) + sc*16;
        v8s p0, p1;
        #pragma unroll
        for (int i = 0; i < 8; i++) ((short*)&p0)[i] = (short)Tsh[(sc*16 + i)*74 + e];
        #pragma unroll
        for (int i = 0; i < 8; i++) ((short*)&p1)[i] = (short)Tsh[(sc*16 + 8 + i)*74 + e];
        bf16_t* dst = vt + ((size_t)b*EN + n0 + e)*SN + sl;
        *(v8s*)dst = p0;
        *(v8s*)(dst + 8) = p1;
    } else {
        #pragma unroll
        for (int r = 0; r < 4; r++){
            int row = m0 + wv*16 + quad*4 + r;
            #pragma unroll
            for (int t = 0; t < 4; t++){
                float y = acc[t][r] + bfv[t];
                if constexpr (EPI == 1) y = fmaxf(y, 0.f);
                stsc(out + (size_t)row*N + n0 + t*16 + col, y);
            }
        }
    }
}

// ---------------------------------------------------------------------------
// gemm_ln (round-4 version): out = LayerNorm(A@W^T + bias + res), N=256.
// Block 64m x 256n; W chunk [256 x 32] staged via global_load_lds, wave-shared.
// ---------------------------------------------------------------------------
template<typename OutT, typename ResT>
__global__ __launch_bounds__(256) void gemm_ln(
    const bf16_t* __restrict__ A, const bf16_t* __restrict__ W,
    const float* __restrict__ bias, const ResT* __restrict__ res,
    const float* __restrict__ gamma, const float* __restrict__ beta,
    OutT* __restrict__ out, int M, int K)
{
    __shared__ __align__(16) bf16_t Wt[256*32];   // 16 KB
    int tid = threadIdx.x;
    int lane = tid & 63, wv = tid >> 6, col = lane & 15, quad = lane >> 4;
    int row0 = blockIdx.x * 64 + wv*16;

    const bf16_t* Arow = A + (size_t)(row0 + col)*K + quad*8;

    v4f acc[16];
    #pragma unroll
    for (int t = 0; t < 16; t++) acc[t] = (v4f){0.f,0.f,0.f,0.f};

    for (int ks = 0; ks < K; ks += 32){
        #pragma unroll
        for (int c = 0; c < 4; c++)
            glds16(W + (size_t)(c*64 + (tid>>2))*K + ks + (tid&3)*8,
                   Wt + c*2048 + wv*512);
        __syncthreads();
        bf16x8 a = ldb8(Arow + ks);
        #pragma unroll
        for (int t = 0; t < 16; t++){
            bf16x8 bf = ldb8(Wt + (t*16 + col)*32 + quad*8);
            acc[t] = MFMA16(a, bf, acc[t]);
        }
        __syncthreads();
    }

    float bfv[16], gf[16], btf[16];
    #pragma unroll
    for (int t = 0; t < 16; t++){
        bfv[t] = bias [t*16 + col];
        gf[t]  = gamma[t*16 + col];
        btf[t] = beta [t*16 + col];
    }
    #pragma unroll
    for (int r = 0; r < 4; r++){
        int row = row0 + quad*4 + r;
        float s1 = 0.f, s2 = 0.f;
        #pragma unroll
        for (int t = 0; t < 16; t++){
            float y = acc[t][r] + bfv[t] + ldsc(res + (size_t)row*EN + t*16 + col);
            acc[t][r] = y;
            s1 += y; s2 += y*y;
        }
        #pragma unroll
        for (int m = 1; m <= 8; m <<= 1){
            s1 += __shfl_xor(s1, m);
            s2 += __shfl_xor(s2, m);
        }
        float mu  = s1 * (1.f/256.f);
        float var = s2 * (1.f/256.f) - mu*mu;
        float rs  = rsqrtf(var + 1e-5f);
        #pragma unroll
        for (int t = 0; t < 16; t++)
            stsc(out + (size_t)row*EN + t*16 + col, (acc[t][r]-mu)*rs*gf[t] + btf[t]);
    }
}

// ---------------------------------------------------------------------------
// Attention round 6: Q=32/block, grid 512, 4 waves.
// Per 64-key chunk: V-tile [256e][64k] staged COALESCED into LDS (double-buf,
// XOR piece-swizzle folded into global src), QK split 16 keys/wave (16x16x32),
// weights via double-buffered LDS tile, PV e-split 64/wave (32x32x16).
// ONE barrier per chunk. No k-split -> no acc combine; den combine only.
// ---------------------------------------------------------------------------
__global__ __launch_bounds__(256, 2) void attn_kernel(
    const bf16_t* __restrict__ xk, const bf16_t* __restrict__ xq,
    const bf16_t* __restrict__ vt, const float* __restrict__ osp,
    bf16_t* __restrict__ ctx)
{
    __shared__ __align__(16) bf16_t Vl[2][256*64];   // 64 KB, piece-swizzled
    __shared__ __align__(16) bf16_t Wtb[2][32*72];   // 9 KB, rows padded to 72
    __shared__ float densh[4][32];
    __shared__ float dent[32];

    int tid  = threadIdx.x;
    int lane = tid & 63;
    int wv   = tid >> 6;
    int col  = lane & 15;
    int quad = lane >> 4;
    int l31  = lane & 31;
    int half = lane >> 5;

    // batch b pinned to XCD pair {2b,2b+1} -> its Vt slice (2 MB) L2-resident
    int bid = blockIdx.x;
    int b   = (bid & 7) >> 1;
    int qi  = ((bid >> 3) << 1) | (bid & 1);
    int q0  = qi * 32;

    float os = osp[0];
    const float c1 = 1.4426950408889634f;
    float k2 = c1 * os;

    const bf16_t* xkb = xk + (size_t)b * SN * PAUG;
    const bf16_t* xqb = xq + (size_t)b * SN * PAUG;
    const bf16_t* vtb = vt + (size_t)b * EN * SN;

    // query fragments, held in registers all kernel
    bf16x8 qf[2][2];
    #pragma unroll
    for (int g2 = 0; g2 < 2; g2++)
        #pragma unroll
        for (int h = 0; h < 2; h++)
            qf[g2][h] = ldb8(xqb + (size_t)(q0 + g2*16 + col)*PAUG + h*32 + quad*8);

    // V staging: thread t covers rows j*32+(t>>3), piece (t&7)^(row&7) of 8
    int erow = tid >> 3;                     // 0..31
    int psw  = (tid & 7) ^ (erow & 7);       // swizzled global piece
    const bf16_t* vsrc = vtb + (size_t)erow * SN + psw*8;

    // prologue: stage chunk 0 into buffer 0
    #pragma unroll
    for (int j = 0; j < 8; j++)
        glds16(vsrc + (size_t)j*32*SN, &Vl[0][j*2048 + tid*8]);

    v16f acc[2];
    #pragma unroll
    for (int en = 0; en < 2; en++)
        #pragma unroll
        for (int i = 0; i < 16; i++) acc[en][i] = 0.f;
    float den[2] = {0.f, 0.f};
    const v4f zero = (v4f){0.f,0.f,0.f,0.f};

    for (int c = 0; c < 64; c++){
        int k0 = c * 64;
        int cb = c & 1;
        // prefetch next V-tile (drained by this iter's barrier; QK covers latency)
        if (c < 63){
            #pragma unroll
            for (int j = 0; j < 8; j++)
                glds16(vsrc + (size_t)j*32*SN + (k0 + 64), &Vl[cb^1][j*2048 + tid*8]);
        }
        // QK for this wave's 16-key slice
        const bf16_t* krow = xkb + (size_t)(k0 + wv*16 + col)*PAUG;
        bf16x8 kf0 = ldb8(krow + quad*8);
        bf16x8 kf1 = ldb8(krow + 32 + quad*8);
        v4f st[2];
        #pragma unroll
        for (int g2 = 0; g2 < 2; g2++){
            st[g2] = MFMA16(kf0, qf[g2][0], zero);
            st[g2] = MFMA16(kf1, qf[g2][1], st[g2]);
        }
        // w = exp(os*exp(st) - os); write to weight tile rows [q][k_local]
        #pragma unroll
        for (int g2 = 0; g2 < 2; g2++)
            #pragma unroll
            for (int rp = 0; rp < 2; rp++){
                float w0 = exp2f(fmaf(k2, exp2f(c1*st[g2][rp*2+0]), -k2));
                float w1 = exp2f(fmaf(k2, exp2f(c1*st[g2][rp*2+1]), -k2));
                den[g2] += w0 + w1;
                uint32_t pk = (uint32_t)f2b(w0) | ((uint32_t)f2b(w1) << 16);
                *(uint32_t*)&Wtb[cb][(g2*16+col)*72 + wv*16 + quad*4 + rp*2] = pk;
            }
        __syncthreads();   // Wtb[cb] + Vl[cb] ready; prev PV (other buffers) done

        // PV: this wave's 64-e slice, 32x32x16 MFMAs
        bf16x8 af[4];
        #pragma unroll
        for (int subk = 0; subk < 4; subk++)
            af[subk] = ldb8(&Wtb[cb][l31*72 + subk*16 + half*8]);
        #pragma unroll
        for (int en = 0; en < 2; en++){
            const bf16_t* vrow = &Vl[cb][(wv*64 + en*32 + l31)*64];
            int sw = l31 & 7;
            #pragma unroll
            for (int subk = 0; subk < 4; subk++){
                bf16x8 bf = ldb8(vrow + ((subk*2 + half) ^ sw)*8);
                acc[en] = MFMA32(af[subk], bf, acc[en]);
            }
        }
    }

    // den: reduce over quads, combine across waves
    #pragma unroll
    for (int g2 = 0; g2 < 2; g2++){
        den[g2] += __shfl_xor(den[g2], 16);
        den[g2] += __shfl_xor(den[g2], 32);
    }
    if (lane < 16){
        densh[wv][lane]      = den[0];
        densh[wv][16 + lane] = den[1];
    }
    __syncthreads();
    if (tid < 32)
        dent[tid] = 1.f / (densh[0][tid] + densh[1][tid] + densh[2][tid] + densh[3][tid]);
    __syncthreads();

    size_t obase = ((size_t)b*SN + q0) * EN + wv*64;
    #pragma unroll
    for (int rg = 0; rg < 16; rg++){
        int row = (rg & 3) + 8*(rg >> 2) + 4*half;
        float inv = dent[row];
        #pragma unroll
        for (int en = 0; en < 2; en++)
            ctx[obase + (size_t)row*EN + en*32 + l31] = f2b(acc[en][rg] * inv);
    }
}

// ---------------------------------------------------------------------------
extern "C" void kernel_launch(void* const* d_in, const int* in_sizes, int n_in,
                              void* d_out, int out_size, void* d_ws, size_t ws_size,
                              hipStream_t stream)
{
    (void)in_sizes; (void)n_in; (void)out_size; (void)ws_size;
    const float* src  = (const float*)d_in[0];
    const float* pos  = (const float*)d_in[1];
    const float* Wpos = (const float*)d_in[2];
    const float* bpos = (const float*)d_in[3];
    const float* ls   = (const float*)d_in[4];
    const float* os   = (const float*)d_in[5];
    const float* Wv   = (const float*)d_in[6];
    const float* bv   = (const float*)d_in[7];
    const float* Wo   = (const float*)d_in[8];
    const float* bo   = (const float*)d_in[9];
    const float* W1   = (const float*)d_in[10];
    const float* b1   = (const float*)d_in[11];
    const float* W2   = (const float*)d_in[12];
    const float* b2   = (const float*)d_in[13];
    const float* g1   = (const float*)d_in[14];
    const float* be1  = (const float*)d_in[15];
    const float* g2   = (const float*)d_in[16];
    const float* be2  = (const float*)d_in[17];

    char* w = (char*)d_ws;
    bf16_t* xkb  = (bf16_t*)(w);                         // 2 MB [B,S,64]
    bf16_t* xqb  = (bf16_t*)(w + ( 2u<<20));             // 2 MB
    bf16_t* Wvb  = (bf16_t*)(w + ( 4u<<20));             // 128 KB
    bf16_t* Wob  = (bf16_t*)(w + ( 4u<<20) + (1u<<18));  // 128 KB
    bf16_t* W1b  = (bf16_t*)(w + ( 5u<<20));             // 512 KB
    bf16_t* W2b  = (bf16_t*)(w + ( 6u<<20));             // 512 KB
    bf16_t* srcb = (bf16_t*)(w + ( 8u<<20));             // 8 MB (dead after vproj)
    bf16_t* ctx  = (bf16_t*)(w + ( 8u<<20));             // aliases srcb
    bf16_t* vtg  = (bf16_t*)(w + (16u<<20));             // 8 MB [B,E,S]
    bf16_t* xws  = (bf16_t*)(w + (24u<<20));             // 8 MB
    bf16_t* hws  = (bf16_t*)(w + (32u<<20));             // 32 MB

    cvt_kernel<<<dim3((BS*EN)>>10), 256, 0, stream>>>(src, srcb);
    cvtw_kernel<<<dim3(640), 256, 0, stream>>>(Wv, Wvb, Wo, Wob, W1, W1b, W2, W2b);
    posxs_kernel<<<dim3(SN/256, BN), 256, 0, stream>>>(pos, Wpos, bpos, ls, xkb, xqb);

    // v = src @ Wv^T + bv  -> transposed store vt[b][e][s]
    gemm_a<3, bf16_t><<<dim3(BS/64, EN/64), 256, 0, stream>>>(
        srcb, Wvb, bv, (bf16_t*)nullptr, vtg, BS, EN, EN);
    // ctx = softmax(os*exp(-0.5*d2)) @ v
    attn_kernel<<<dim3(512), 256, 0, stream>>>(xkb, xqb, vtg, os, ctx);
    // x = LN1(src + ctx @ Wo^T + bo)
    gemm_ln<bf16_t, float><<<dim3(BS/64), 256, 0, stream>>>(
        ctx, Wob, bo, src, g1, be1, xws, BS, EN);
    // h = relu(x @ W1^T + b1)
    gemm_a<1, bf16_t><<<dim3(BS/64, FN/64), 256, 0, stream>>>(
        xws, W1b, b1, hws, (bf16_t*)nullptr, BS, FN, EN);
    // out = LN2(x + h @ W2^T + b2) -> fp32
    gemm_ln<float, bf16_t><<<dim3(BS/64), 256, 0, stream>>>(
        hws, W2b, b2, xws, g2, be2, (float*)d_out, BS, FN);
}

// Round 7
// 302.673 us; speedup vs baseline: 1.7776x; 1.0055x over previous
//
#include <hip/hip_runtime.h>
#include <stdint.h>

#define BN 4
#define SN 4096
#define EN 256
#define PN 32
#define FN 1024
#define BS (BN*SN)   // 16384
#define PAUG 64      // 32 xs chans + aug (+ zero pad to 64)

typedef uint16_t bf16_t;
typedef short v4s  __attribute__((ext_vector_type(4)));
typedef short v8s  __attribute__((ext_vector_type(8)));
typedef __bf16 bf16x8 __attribute__((ext_vector_type(8)));
typedef float v4f   __attribute__((ext_vector_type(4)));
typedef float v16f  __attribute__((ext_vector_type(16)));

#define MFMA16(a,b,c) __builtin_amdgcn_mfma_f32_16x16x32_bf16(a,b,c,0,0,0)
#define MFMA32(a,b,c) __builtin_amdgcn_mfma_f32_32x32x16_bf16(a,b,c,0,0,0)

__device__ __forceinline__ float b2f(bf16_t x){
    uint32_t u = ((uint32_t)x) << 16; float f; __builtin_memcpy(&f, &u, 4); return f;
}
__device__ __forceinline__ bf16_t f2b(float f){
    uint32_t u; __builtin_memcpy(&u, &f, 4);
    u += 0x7FFFu + ((u >> 16) & 1u);           // RNE
    return (bf16_t)(u >> 16);
}
__device__ __forceinline__ bf16x8 ldb8(const bf16_t* p){
    v8s r = *(const v8s*)p; return __builtin_bit_cast(bf16x8, r);
}
__device__ __forceinline__ float ldsc(const float* p){ return *p; }
__device__ __forceinline__ float ldsc(const bf16_t* p){ return b2f(*p); }
__device__ __forceinline__ void stsc(float* p, float v){ *p = v; }
__device__ __forceinline__ void stsc(bf16_t* p, float v){ *p = f2b(v); }

#if __has_builtin(__builtin_amdgcn_cvt_pk_bf16_f32)
typedef __bf16 bf16x2 __attribute__((ext_vector_type(2)));
__device__ __forceinline__ uint32_t pkbf16(float a, float b){
    bf16x2 r = __builtin_amdgcn_cvt_pk_bf16_f32(a, b);
    return __builtin_bit_cast(uint32_t, r);
}
#else
__device__ __forceinline__ uint32_t pkbf16(float a, float b){
    return (uint32_t)f2b(a) | ((uint32_t)f2b(b) << 16);
}
#endif

typedef const __attribute__((address_space(1))) uint32_t* glds_gp;
typedef __attribute__((address_space(3))) uint32_t* glds_lp;
__device__ __forceinline__ void glds16(const bf16_t* g, bf16_t* l){
    __builtin_amdgcn_global_load_lds((glds_gp)g, (glds_lp)l, 16, 0, 0);
}

// ---------------------------------------------------------------------------
// fp32 -> bf16 converters
// ---------------------------------------------------------------------------
__global__ __launch_bounds__(256) void cvt_kernel(
    const float* __restrict__ in, bf16_t* __restrict__ out)
{
    int i = (blockIdx.x * 256 + threadIdx.x) * 4;
    float4 f = *(const float4*)(in + i);
    v4s o;
    o.x = (short)f2b(f.x); o.y = (short)f2b(f.y);
    o.z = (short)f2b(f.z); o.w = (short)f2b(f.w);
    *(v4s*)(out + i) = o;
}

__global__ __launch_bounds__(256) void cvtw_kernel(
    const float* __restrict__ a, bf16_t* __restrict__ da,
    const float* __restrict__ b, bf16_t* __restrict__ db,
    const float* __restrict__ c, bf16_t* __restrict__ dc,
    const float* __restrict__ d, bf16_t* __restrict__ dd)
{
    int i = (blockIdx.x * 256 + threadIdx.x) * 4;
    const float* src; bf16_t* dst; int off;
    if      (i <  65536){ src=a; dst=da; off=i; }
    else if (i < 131072){ src=b; dst=db; off=i- 65536; }
    else if (i < 393216){ src=c; dst=dc; off=i-131072; }
    else                { src=d; dst=dd; off=i-393216; }
    float4 f = *(const float4*)(src + off);
    v4s o;
    o.x = (short)f2b(f.x); o.y = (short)f2b(f.y);
    o.z = (short)f2b(f.z); o.w = (short)f2b(f.w);
    *(v4s*)(dst + off) = o;
}

// ---------------------------------------------------------------------------
// posxs: pe = Wpos @ pos_embed + bpos; xs = pe/ls (bf16).
// Key rows [xs, -sq/2, 1, 0..]; query rows pre-scaled by c1=log2(e):
// [c1*xs, c1, -c1*sq/2, 0..] so QK MFMA yields c1*st directly (exp2-ready).
// ---------------------------------------------------------------------------
__global__ __launch_bounds__(256) void posxs_kernel(
    const float* __restrict__ pos, const float* __restrict__ Wp,
    const float* __restrict__ bp,  const float* __restrict__ lsp,
    bf16_t* __restrict__ xk, bf16_t* __restrict__ xq)
{
    __shared__ float Wsh[PN*PN];
    __shared__ float bsh[PN];
    int tid = threadIdx.x;
    for (int i = tid; i < PN*PN; i += 256) Wsh[i] = Wp[i];
    if (tid < PN) bsh[tid] = bp[tid];
    __syncthreads();

    int s = blockIdx.x * 256 + tid;
    int b = blockIdx.y;
    float inv_ls = 1.0f / lsp[0];
    const float c1f = 1.4426950408889634f;

    float col[PN];
    #pragma unroll
    for (int p = 0; p < PN; p++) col[p] = pos[((size_t)b*PN + p)*SN + s];

    uint16_t xb[PN], qb[PN];
    float sq = 0.f;
    #pragma unroll 4
    for (int o = 0; o < PN; o++){
        float pe = bsh[o];
        #pragma unroll
        for (int p = 0; p < PN; p++) pe += col[p] * Wsh[o*PN + p];
        float pv = pe * inv_ls;
        uint16_t h = f2b(pv);
        xb[o] = h;
        qb[o] = f2b(c1f * pv);
        float xr = b2f(h);
        sq += xr * xr;
    }

    size_t base = ((size_t)b*SN + s) * PAUG;
    v8s pk[8];
    // key rows
    #pragma unroll
    for (int c = 0; c < 4; c++)
        #pragma unroll
        for (int j = 0; j < 8; j++) ((short*)&pk[c])[j] = (short)xb[c*8 + j];
    #pragma unroll
    for (int c = 4; c < 8; c++)
        #pragma unroll
        for (int j = 0; j < 8; j++) ((short*)&pk[c])[j] = 0;
    ((short*)&pk[4])[0] = (short)f2b(-0.5f * sq);
    ((short*)&pk[4])[1] = (short)0x3F80;   // 1.0
    #pragma unroll
    for (int c = 0; c < 8; c++) *(v8s*)(xk + base + c*8) = pk[c];

    // query rows (c1-scaled)
    #pragma unroll
    for (int c = 0; c < 4; c++)
        #pragma unroll
        for (int j = 0; j < 8; j++) ((short*)&pk[c])[j] = (short)qb[c*8 + j];
    ((short*)&pk[4])[0] = (short)f2b(c1f);
    ((short*)&pk[4])[1] = (short)f2b(-0.5f * sq * c1f);
    #pragma unroll
    for (int c = 0; c < 8; c++) *(v8s*)(xq + base + c*8) = pk[c];
}

// ---------------------------------------------------------------------------
// gemm_a: out = A @ W^T (+bias, opt relu). Block 64m x 64n, 4 waves on m.
// Entire W-tile [64n x K] (K<=256) staged once via global_load_lds; one barrier.
// EPI 0: bias ; 1: relu ; 3: bias -> transposed store vt[b][e][s]
// ---------------------------------------------------------------------------
template<int EPI, typename OutT>
__global__ __launch_bounds__(256) void gemm_a(
    const bf16_t* __restrict__ A, const bf16_t* __restrict__ W,
    const float* __restrict__ bias, OutT* __restrict__ out,
    bf16_t* __restrict__ vt, int M, int N, int K)
{
    __shared__ __align__(16) bf16_t Wt[8*2048];   // 32 KB max
    int tid = threadIdx.x;
    int lane = tid & 63, wv = tid >> 6, col = lane & 15, quad = lane >> 4;
    int m0 = blockIdx.x * 64, n0 = blockIdx.y * 64;
    int nck = K >> 5;

    const bf16_t* wsrc = W + (size_t)(n0 + (tid>>2))*K + (tid&3)*8;
    for (int r = 0; r < nck; r++)
        glds16(wsrc + r*32, Wt + r*2048 + tid*8);

    const bf16_t* Arow = A + (size_t)(m0 + wv*16 + col)*K + quad*8;

    v4f acc[4];
    #pragma unroll
    for (int t = 0; t < 4; t++) acc[t] = (v4f){0.f,0.f,0.f,0.f};

    __syncthreads();

    for (int c = 0; c < nck; c++){
        bf16x8 a = ldb8(Arow + c*32);
        #pragma unroll
        for (int t = 0; t < 4; t++){
            bf16x8 bf = ldb8(Wt + c*2048 + (t*16 + col)*32 + quad*8);
            acc[t] = MFMA16(a, bf, acc[t]);
        }
    }

    float bfv[4];
    #pragma unroll
    for (int t = 0; t < 4; t++) bfv[t] = bias[n0 + t*16 + col];

    if constexpr (EPI == 3){
        __shared__ uint16_t Tsh[64*74];
        #pragma unroll
        for (int r = 0; r < 4; r++)
            #pragma unroll
            for (int t = 0; t < 4; t++)
                Tsh[(wv*16 + quad*4 + r)*74 + t*16 + col] = f2b(acc[t][r] + bfv[t]);
        __syncthreads();
        int e = tid >> 2, sc = tid & 3;
        int b = m0 >> 12;
        int sl = (m0 & (SN-1)) + sc*16;
        v8s p0, p1;
        #pragma unroll
        for (int i = 0; i < 8; i++) ((short*)&p0)[i] = (short)Tsh[(sc*16 + i)*74 + e];
        #pragma unroll
        for (int i = 0; i < 8; i++) ((short*)&p1)[i] = (short)Tsh[(sc*16 + 8 + i)*74 + e];
        bf16_t* dst = vt + ((size_t)b*EN + n0 + e)*SN + sl;
        *(v8s*)dst = p0;
        *(v8s*)(dst + 8) = p1;
    } else {
        #pragma unroll
        for (int r = 0; r < 4; r++){
            int row = m0 + wv*16 + quad*4 + r;
            #pragma unroll
            for (int t = 0; t < 4; t++){
                float y = acc[t][r] + bfv[t];
                if constexpr (EPI == 1) y = fmaxf(y, 0.f);
                stsc(out + (size_t)row*N + n0 + t*16 + col, y);
            }
        }
    }
}

// ---------------------------------------------------------------------------
// gemm_b: out = A @ W^T + bias, any K multiple of 128. Block 64m x 64n.
// W staged in 128k chunks, double-buffered, skewed: prefetch issued right
// after the barrier, consumed one full chunk later.
// ---------------------------------------------------------------------------
template<int RELU, typename OutT>
__global__ __launch_bounds__(256) void gemm_b(
    const bf16_t* __restrict__ A, const bf16_t* __restrict__ W,
    const float* __restrict__ bias, OutT* __restrict__ out,
    int N, int K)
{
    __shared__ __align__(16) bf16_t Wt[2][64*128];   // 2 x 16 KB
    int tid = threadIdx.x;
    int lane = tid & 63, wv = tid >> 6, col = lane & 15, quad = lane >> 4;
    int m0 = blockIdx.x * 64, n0 = blockIdx.y * 64;
    int nck = K >> 7;

    const bf16_t* wsrc = W + (size_t)(n0 + (tid>>2))*K + (tid&3)*8;
    const bf16_t* Arow = A + (size_t)(m0 + wv*16 + col)*K + quad*8;

    #pragma unroll
    for (int s = 0; s < 4; s++)
        glds16(wsrc + s*32, &Wt[0][s*2048 + tid*8]);

    v4f acc[4];
    #pragma unroll
    for (int t = 0; t < 4; t++) acc[t] = (v4f){0.f,0.f,0.f,0.f};

    __syncthreads();

    for (int c = 0; c < nck; c++){
        int cb = c & 1;
        if (c + 1 < nck){
            #pragma unroll
            for (int s = 0; s < 4; s++)
                glds16(wsrc + (c+1)*128 + s*32, &Wt[cb^1][s*2048 + tid*8]);
        }
        #pragma unroll
        for (int s = 0; s < 4; s++){
            bf16x8 a = ldb8(Arow + c*128 + s*32);
            #pragma unroll
            for (int t = 0; t < 4; t++){
                bf16x8 bf = ldb8(&Wt[cb][s*2048 + (t*16 + col)*32 + quad*8]);
                acc[t] = MFMA16(a, bf, acc[t]);
            }
        }
        __syncthreads();
    }

    float bfv[4];
    #pragma unroll
    for (int t = 0; t < 4; t++) bfv[t] = bias[n0 + t*16 + col];
    #pragma unroll
    for (int r = 0; r < 4; r++){
        int row = m0 + wv*16 + quad*4 + r;
        #pragma unroll
        for (int t = 0; t < 4; t++){
            float y = acc[t][r] + bfv[t];
            if constexpr (RELU) y = fmaxf(y, 0.f);
            stsc(out + (size_t)row*N + n0 + t*16 + col, y);
        }
    }
}

// ---------------------------------------------------------------------------
// ln_kernel: out = LayerNorm(y + res) * gamma + beta.  y is bf16 (bias already
// applied in the GEMM). Block 256 thr = 32 rows x 8 lanes; memory-bound.
// ---------------------------------------------------------------------------
template<typename OutT, typename ResT>
__global__ __launch_bounds__(256) void ln_kernel(
    const bf16_t* __restrict__ y, const ResT* __restrict__ res,
    const float* __restrict__ gamma, const float* __restrict__ beta,
    OutT* __restrict__ out)
{
    int tid = threadIdx.x;
    int row = blockIdx.x * 32 + (tid >> 3);
    int l8  = tid & 7;
    size_t base = (size_t)row * EN;
    float v[32];
    float s1 = 0.f, s2 = 0.f;
    #pragma unroll
    for (int i = 0; i < 4; i++){
        int off = l8*8 + i*64;
        v8s a = *(const v8s*)(y + base + off);
        #pragma unroll
        for (int j = 0; j < 8; j++){
            float t = b2f((bf16_t)(uint16_t)a[j]) + ldsc(res + base + off + j);
            v[i*8 + j] = t; s1 += t; s2 += t*t;
        }
    }
    #pragma unroll
    for (int m = 1; m <= 4; m <<= 1){
        s1 += __shfl_xor(s1, m);
        s2 += __shfl_xor(s2, m);
    }
    float mu = s1 * (1.f/256.f);
    float rs = rsqrtf(s2 * (1.f/256.f) - mu*mu + 1e-5f);
    #pragma unroll
    for (int i = 0; i < 4; i++){
        int off = l8*8 + i*64;
        #pragma unroll
        for (int j = 0; j < 8; j++)
            stsc(out + base + off + j, (v[i*8+j]-mu)*rs*gamma[off+j] + beta[off+j]);
    }
}

// ---------------------------------------------------------------------------
// Attention round 7: Q=32/block, grid 512, skewed pipeline.
// Per chunk: barrier -> prefetch V(c+1) -> QK+exp(c+1) -> PV(c) -> barrier.
// The glds gets a full chunk before its draining barrier (no m97 stall).
// ---------------------------------------------------------------------------
__device__ __forceinline__ void qk_exp(
    const bf16_t* __restrict__ xkb, const bf16x8 (&qf)[2][2], int k0,
    int wv, int col, int quad, float k2, bf16_t* __restrict__ WtbDst,
    float (&den)[2])
{
    const v4f zero = (v4f){0.f,0.f,0.f,0.f};
    const bf16_t* krow = xkb + (size_t)(k0 + wv*16 + col)*PAUG;
    bf16x8 kf0 = ldb8(krow + quad*8);
    bf16x8 kf1 = ldb8(krow + 32 + quad*8);
    #pragma unroll
    for (int g2 = 0; g2 < 2; g2++){
        v4f st = MFMA16(kf0, qf[g2][0], zero);
        st = MFMA16(kf1, qf[g2][1], st);
        #pragma unroll
        for (int rp = 0; rp < 2; rp++){
            float e0 = exp2f(st[rp*2+0]);            // st pre-scaled by c1
            float e1 = exp2f(st[rp*2+1]);
            float w0 = exp2f(fmaf(k2, e0, -k2));     // exp(os*exp(st)-os)
            float w1 = exp2f(fmaf(k2, e1, -k2));
            den[g2] += w0 + w1;
            *(uint32_t*)&WtbDst[(g2*16+col)*72 + wv*16 + quad*4 + rp*2] = pkbf16(w0, w1);
        }
    }
}

__global__ __launch_bounds__(256, 2) void attn_kernel(
    const bf16_t* __restrict__ xk, const bf16_t* __restrict__ xq,
    const bf16_t* __restrict__ vt, const float* __restrict__ osp,
    bf16_t* __restrict__ ctx)
{
    __shared__ __align__(16) bf16_t Vl[2][256*64];   // 64 KB, piece-swizzled
    __shared__ __align__(16) bf16_t Wtb[2][32*72];   // 9 KB
    __shared__ float densh[4][32];
    __shared__ float dent[32];

    int tid  = threadIdx.x;
    int lane = tid & 63;
    int wv   = tid >> 6;
    int col  = lane & 15;
    int quad = lane >> 4;
    int l31  = lane & 31;
    int half = lane >> 5;

    int bid = blockIdx.x;
    int b   = (bid & 7) >> 1;
    int qi  = ((bid >> 3) << 1) | (bid & 1);
    int q0  = qi * 32;

    float k2 = 1.4426950408889634f * osp[0];

    const bf16_t* xkb = xk + (size_t)b * SN * PAUG;
    const bf16_t* xqb = xq + (size_t)b * SN * PAUG;
    const bf16_t* vtb = vt + (size_t)b * EN * SN;

    bf16x8 qf[2][2];
    #pragma unroll
    for (int g2 = 0; g2 < 2; g2++)
        #pragma unroll
        for (int h = 0; h < 2; h++)
            qf[g2][h] = ldb8(xqb + (size_t)(q0 + g2*16 + col)*PAUG + h*32 + quad*8);

    int erow = tid >> 3;                     // 0..31
    int psw  = (tid & 7) ^ (erow & 7);       // swizzled global piece
    const bf16_t* vsrc = vtb + (size_t)erow * SN + psw*8;

    v16f acc[2];
    #pragma unroll
    for (int en = 0; en < 2; en++)
        #pragma unroll
        for (int i = 0; i < 16; i++) acc[en][i] = 0.f;
    float den[2] = {0.f, 0.f};

    // prologue: stage V chunk 0, compute weights chunk 0
    #pragma unroll
    for (int j = 0; j < 8; j++)
        glds16(vsrc + (size_t)j*32*SN, &Vl[0][j*2048 + tid*8]);
    qk_exp(xkb, qf, 0, wv, col, quad, k2, &Wtb[0][0], den);
    __syncthreads();

    for (int c = 0; c < 64; c++){
        int cb = c & 1;
        if (c < 63){
            // prefetch V chunk c+1 (drained by NEXT barrier, one chunk away)
            #pragma unroll
            for (int j = 0; j < 8; j++)
                glds16(vsrc + (size_t)j*32*SN + (c+1)*64, &Vl[cb^1][j*2048 + tid*8]);
            // weights for chunk c+1 into the other buffer
            qk_exp(xkb, qf, (c+1)*64, wv, col, quad, k2, &Wtb[cb^1][0], den);
        }
        // PV chunk c: this wave's 64-e slice, 32x32x16 MFMAs
        bf16x8 af[4];
        #pragma unroll
        for (int subk = 0; subk < 4; subk++)
            af[subk] = ldb8(&Wtb[cb][l31*72 + subk*16 + half*8]);
        int sw = l31 & 7;
        #pragma unroll
        for (int en = 0; en < 2; en++){
            const bf16_t* vrow = &Vl[cb][(wv*64 + en*32 + l31)*64];
            #pragma unroll
            for (int subk = 0; subk < 4; subk++){
                bf16x8 bf = ldb8(vrow + ((subk*2 + half) ^ sw)*8);
                acc[en] = MFMA32(af[subk], bf, acc[en]);
            }
        }
        __syncthreads();
    }

    #pragma unroll
    for (int g2 = 0; g2 < 2; g2++){
        den[g2] += __shfl_xor(den[g2], 16);
        den[g2] += __shfl_xor(den[g2], 32);
    }
    if (lane < 16){
        densh[wv][lane]      = den[0];
        densh[wv][16 + lane] = den[1];
    }
    __syncthreads();
    if (tid < 32)
        dent[tid] = 1.f / (densh[0][tid] + densh[1][tid] + densh[2][tid] + densh[3][tid]);
    __syncthreads();

    size_t obase = ((size_t)b*SN + q0) * EN + wv*64;
    #pragma unroll
    for (int rg = 0; rg < 16; rg++){
        int row = (rg & 3) + 8*(rg >> 2) + 4*half;
        float inv = dent[row];
        #pragma unroll
        for (int en = 0; en < 2; en++)
            ctx[obase + (size_t)row*EN + en*32 + l31] = f2b(acc[en][rg] * inv);
    }
}

// ---------------------------------------------------------------------------
extern "C" void kernel_launch(void* const* d_in, const int* in_sizes, int n_in,
                              void* d_out, int out_size, void* d_ws, size_t ws_size,
                              hipStream_t stream)
{
    (void)in_sizes; (void)n_in; (void)out_size; (void)ws_size;
    const float* src  = (const float*)d_in[0];
    const float* pos  = (const float*)d_in[1];
    const float* Wpos = (const float*)d_in[2];
    const float* bpos = (const float*)d_in[3];
    const float* ls   = (const float*)d_in[4];
    const float* os   = (const float*)d_in[5];
    const float* Wv   = (const float*)d_in[6];
    const float* bv   = (const float*)d_in[7];
    const float* Wo   = (const float*)d_in[8];
    const float* bo   = (const float*)d_in[9];
    const float* W1   = (const float*)d_in[10];
    const float* b1   = (const float*)d_in[11];
    const float* W2   = (const float*)d_in[12];
    const float* b2   = (const float*)d_in[13];
    const float* g1   = (const float*)d_in[14];
    const float* be1  = (const float*)d_in[15];
    const float* g2   = (const float*)d_in[16];
    const float* be2  = (const float*)d_in[17];

    char* w = (char*)d_ws;
    bf16_t* xkb  = (bf16_t*)(w);                         // 2 MB [B,S,64]
    bf16_t* xqb  = (bf16_t*)(w + ( 2u<<20));             // 2 MB
    bf16_t* Wvb  = (bf16_t*)(w + ( 4u<<20));             // 128 KB
    bf16_t* Wob  = (bf16_t*)(w + ( 4u<<20) + (1u<<18));  // 128 KB
    bf16_t* W1b  = (bf16_t*)(w + ( 5u<<20));             // 512 KB
    bf16_t* W2b  = (bf16_t*)(w + ( 6u<<20));             // 512 KB
    bf16_t* srcb = (bf16_t*)(w + ( 8u<<20));             // 8 MB (dead after vproj)
    bf16_t* ctx  = (bf16_t*)(w + ( 8u<<20));             // aliases srcb
    bf16_t* y2   = (bf16_t*)(w + ( 8u<<20));             // aliases ctx (dead after Wo-gemm)
    bf16_t* vtg  = (bf16_t*)(w + (16u<<20));             // 8 MB [B,E,S] (dead after attn)
    bf16_t* y1   = (bf16_t*)(w + (16u<<20));             // aliases vtg
    bf16_t* xws  = (bf16_t*)(w + (24u<<20));             // 8 MB
    bf16_t* hws  = (bf16_t*)(w + (32u<<20));             // 32 MB

    cvt_kernel<<<dim3((BS*EN)>>10), 256, 0, stream>>>(src, srcb);
    cvtw_kernel<<<dim3(640), 256, 0, stream>>>(Wv, Wvb, Wo, Wob, W1, W1b, W2, W2b);
    posxs_kernel<<<dim3(SN/256, BN), 256, 0, stream>>>(pos, Wpos, bpos, ls, xkb, xqb);

    // v = src @ Wv^T + bv  -> transposed store vt[b][e][s]
    gemm_a<3, bf16_t><<<dim3(BS/64, EN/64), 256, 0, stream>>>(
        srcb, Wvb, bv, (bf16_t*)nullptr, vtg, BS, EN, EN);
    // ctx = softmax(os*exp(-0.5*d2)) @ v
    attn_kernel<<<dim3(512), 256, 0, stream>>>(xkb, xqb, vtg, os, ctx);
    // y1 = ctx @ Wo^T + bo ; x = LN1(y1 + src)
    gemm_a<0, bf16_t><<<dim3(BS/64, EN/64), 256, 0, stream>>>(
        ctx, Wob, bo, y1, (bf16_t*)nullptr, BS, EN, EN);
    ln_kernel<bf16_t, float><<<dim3(BS/32), 256, 0, stream>>>(y1, src, g1, be1, xws);
    // h = relu(x @ W1^T + b1)
    gemm_a<1, bf16_t><<<dim3(BS/64, FN/64), 256, 0, stream>>>(
        xws, W1b, b1, hws, (bf16_t*)nullptr, BS, FN, EN);
    // y2 = h @ W2^T + b2 ; out = LN2(y2 + x) -> fp32
    gemm_b<0, bf16_t><<<dim3(BS/64, EN/64), 256, 0, stream>>>(
        hws, W2b, b2, y2, EN, FN);
    ln_kernel<float, bf16_t><<<dim3(BS/32), 256, 0, stream>>>(y2, xws, g2, be2, (float*)d_out);
}